// Round 3
// baseline (458.859 us; speedup 1.0000x reference)
//
#include <hip/hip_runtime.h>

// ---------------------------------------------------------------------------
// TransformerBlock (B=4,S=2048,E=1024,H=16,Dh=64), fp32 (or bf16) in, fp32
// (or bf16) out — dtype auto-detected; all compute in bf16 MFMA w/ fp32 accum.
// Pipeline: cvt-to-bf16 -> fused QKV gemm -> flash attn -> Wo gemm (+x) ->
//           norm1 -> FFN1 (relu) -> FFN2 (+h) -> norm2 -> out
// R7: attn K/V double-buffer with raw s_barrier + s_waitcnt vmcnt(4).
// R10: GEMM = gemm2<EPI>: 256x256 tile, BK=64, 512 thr (8 waves 2Mx4N,
//      per-wave 128x64, acc[8][4]), 2 LDS buffers x 64KB.  4 phases/step of
//      {12 ds_read_b128 frags ; stage quarters ; barrier ; setprio 16 MFMA}.
//      Quarter-granular staggered staging: step t stages t+1 as
//      ph0:B0..B3, ph1:A0,A2, ph2:A1,A3; waits vmcnt(2) at step start,
//      vmcnt(6) before ph2 (never 0 until tail).  XCD-bijective block
//      swizzle: on-XCD blocks share the B-panel (resident 512KB/XCD-L2).
// ---------------------------------------------------------------------------

typedef __attribute__((ext_vector_type(8))) short s16x8;
typedef __attribute__((ext_vector_type(4))) short s16x4;
typedef __attribute__((ext_vector_type(4))) unsigned short u16x4;
typedef __attribute__((ext_vector_type(4))) float f32x4;

__device__ __forceinline__ float bf2f(unsigned short u) {
  unsigned int v = ((unsigned int)u) << 16;
  return __builtin_bit_cast(float, v);
}
__device__ __forceinline__ unsigned short f2bf(float f) {
  unsigned int u = __builtin_bit_cast(unsigned int, f);
  u += 0x7fffu + ((u >> 16) & 1u);   // RNE
  return (unsigned short)(u >> 16);
}
// pack two f32 -> two bf16 (truncate) in one v_perm_b32
__device__ __forceinline__ unsigned int pkbf_trunc(float f0, float f1) {
  return __builtin_amdgcn_perm(__builtin_bit_cast(unsigned int, f1),
                               __builtin_bit_cast(unsigned int, f0), 0x07060302u);
}
__device__ __forceinline__ f32x4 mfma16(s16x8 a, s16x8 b, f32x4 c) {
  return __builtin_amdgcn_mfma_f32_16x16x32_bf16(a, b, c, 0, 0, 0);
}
__device__ __forceinline__ void gl2lds16(const unsigned short* g, unsigned short* l) {
  __builtin_amdgcn_global_load_lds(
      (const __attribute__((address_space(1))) unsigned int*)(g),
      (__attribute__((address_space(3))) unsigned int*)(l), 16, 0, 0);
}

// ---------------------------------------------------------------------------
__global__ void detect_dtype(const unsigned int* __restrict__ x, int* __restrict__ flag) {
  const int tid = threadIdx.x;
  int cnt = 0;
  for (int i = tid; i < 2048; i += 256) {
    const unsigned e = (x[i] >> 7) & 0xFF;
    cnt += (e >= 100 && e <= 150) ? 1 : 0;
  }
#pragma unroll
  for (int off = 32; off >= 1; off >>= 1) cnt += __shfl_xor(cnt, off);
  __shared__ int red[4];
  if ((tid & 63) == 0) red[tid >> 6] = cnt;
  __syncthreads();
  if (tid == 0) *flag = ((red[0] + red[1] + red[2] + red[3]) > 1536) ? 1 : 0;
}

// ---------------------------------------------------------------------------
struct CvtArgs {
  const void* src[17];
  unsigned short* dst[17];
  int cum4[18];
};

__global__ __launch_bounds__(256) void cvt_all(CvtArgs a, const int* __restrict__ flag, int total4) {
  const int i = blockIdx.x * 256 + threadIdx.x;
  if (i >= total4) return;
  int lo = 0, hi = 17;
  while (hi - lo > 1) {
    const int mid = (lo + hi) >> 1;
    if (i >= a.cum4[mid]) lo = mid; else hi = mid;
  }
  const int off4 = i - a.cum4[lo];
  if (*flag) {
    const u16x4* s = (const u16x4*)a.src[lo];
    *(u16x4*)&a.dst[lo][off4 * 4] = s[off4];
  } else {
    const float4* s = (const float4*)a.src[lo];
    const float4 v = s[off4];
    u16x4 o;
    o[0] = f2bf(v.x); o[1] = f2bf(v.y); o[2] = f2bf(v.z); o[3] = f2bf(v.w);
    *(u16x4*)&a.dst[lo][off4 * 4] = o;
  }
}

// ---------------------------------------------------------------------------
// GEMM: C = A(MxK) * W(NxK)^T + bias.  256x256 tile, BK=64, 512 threads.
// EPI 2: += resid. EPI 3: relu. EPI 4: fused QKV split (Q scaled, V^T scatter).
// ---------------------------------------------------------------------------
#define QOFF 8388608L
#define SCALE2 0.18033688011f  // (1/8) * log2(e)

template <int EPI>
__global__ __launch_bounds__(512, 1) void gemm2(
    const unsigned short* __restrict__ A, const unsigned short* __restrict__ W,
    const unsigned short* __restrict__ bias, const unsigned short* __restrict__ resid,
    unsigned short* __restrict__ out, int M, int N, int K) {
  extern __shared__ unsigned short sh[];   // 2 * 32768 shorts = 128 KB

  const int tid = threadIdx.x;
  const int lane = tid & 63;
  const int wave = tid >> 6;
  const int qd = lane >> 4;
  const int c = lane & 15;
  const int wr = (wave >> 2) * 128;   // M-half
  const int wc = (wave & 3) * 64;     // N-quarter

  // XCD-bijective block swizzle (nwg % 8 == 0 for all our grids).
  const int nx = gridDim.x, ny = gridDim.y;
  const int nwg = nx * ny;
  int lin = blockIdx.y * nx + blockIdx.x;
  lin = (lin & 7) * (nwg >> 3) + (lin >> 3);
  const int by = lin % ny;            // M varies fastest within an XCD chunk
  const int bx = lin / ny;            // -> B-panel resident per XCD-L2
  const long m0 = (long)by * 256;
  const long n0 = (long)bx * 256;

  // staging: thread owns row (tid>>3) of a 64-row quarter, chunk tid&7,
  // source col XOR-swizzled so LDS dest stays linear; reads unswizzle.
  const int srow = tid >> 3;
  const int scc = ((tid & 7) ^ (srow & 7)) * 8;
  const unsigned short* Asrc = A + (m0 + srow) * (long)K + scc;
  const unsigned short* Wsrc = W + (n0 + srow) * (long)K + scc;
  const int lofs = tid * 8;

  f32x4 acc[8][4] = {};

  const int NT = K >> 6;

  // stage quarter q (64 rows) of A or B for K-step tt into buffer tt&1
  auto stageA = [&](int tt, int q) {
    gl2lds16(Asrc + (long)q * 64 * K + (long)tt * 64,
             sh + (tt & 1) * 32768 + q * 4096 + lofs);
  };
  auto stageB = [&](int tt, int q) {
    gl2lds16(Wsrc + (long)q * 64 * K + (long)tt * 64,
             sh + (tt & 1) * 32768 + 16384 + q * 4096 + lofs);
  };

  // prologue: stage step 0 in steady-state issue order
  stageB(0, 0); stageB(0, 1); stageB(0, 2); stageB(0, 3);
  stageA(0, 0); stageA(0, 2); stageA(0, 1); stageA(0, 3);

  for (int t = 0; t < NT; ++t) {
    const unsigned short* Ab = sh + (t & 1) * 32768;
    const unsigned short* Bb = Ab + 16384;
    const bool dost = (t + 1 < NT);

#pragma unroll
    for (int ph = 0; ph < 4; ++ph) {
      const int qm = ph >> 1, qn = ph & 1;
      // phase-start wait + barrier
      if (ph == 0)
        asm volatile("s_waitcnt vmcnt(2)\n\ts_barrier" ::: "memory");
      else if (ph == 2) {
        if (dost) asm volatile("s_waitcnt vmcnt(6)\n\ts_barrier" ::: "memory");
        else      asm volatile("s_waitcnt vmcnt(0)\n\ts_barrier" ::: "memory");
      } else
        asm volatile("s_barrier" ::: "memory");

      // fragment ds_reads for quadrant (qm, qn)
      s16x8 af[4][2], bfr[2][2];
#pragma unroll
      for (int ks = 0; ks < 2; ++ks) {
#pragma unroll
        for (int mt = 0; mt < 4; ++mt)
          af[mt][ks] = *(const s16x8*)&Ab[(wr + qm * 64 + mt * 16 + c) * 64 +
                                          (((ks * 4 + qd) ^ (c & 7)) * 8)];
#pragma unroll
        for (int nt = 0; nt < 2; ++nt)
          bfr[nt][ks] = *(const s16x8*)&Bb[(wc + qn * 32 + nt * 16 + c) * 64 +
                                           (((ks * 4 + qd) ^ (c & 7)) * 8)];
      }

      // staggered staging of step t+1
      if (dost) {
        if (ph == 0) { stageB(t + 1, 0); stageB(t + 1, 1); stageB(t + 1, 2); stageB(t + 1, 3); }
        else if (ph == 1) { stageA(t + 1, 0); stageA(t + 1, 2); }
        else if (ph == 2) { stageA(t + 1, 1); stageA(t + 1, 3); }
      }

      __builtin_amdgcn_s_setprio(1);
#pragma unroll
      for (int mt = 0; mt < 4; ++mt)
#pragma unroll
        for (int nt = 0; nt < 2; ++nt)
#pragma unroll
          for (int ks = 0; ks < 2; ++ks)
            acc[qm * 4 + mt][qn * 2 + nt] =
                mfma16(af[mt][ks], bfr[nt][ks], acc[qm * 4 + mt][qn * 2 + nt]);
      __builtin_amdgcn_s_setprio(0);
    }
  }

#pragma unroll
  for (int nt = 0; nt < 4; ++nt) {
    const int gn = (int)n0 + wc + nt * 16 + c;
    const float bv = bf2f(bias[gn]);
#pragma unroll
    for (int mt = 0; mt < 8; ++mt) {
      const long gmb = m0 + wr + mt * 16 + qd * 4;
      if constexpr (EPI == 2) {
#pragma unroll
        for (int r = 0; r < 4; ++r) {
          const long gm = gmb + r;
          const float v = acc[mt][nt][r] + bv + bf2f(resid[gm * N + gn]);
          out[gm * N + gn] = f2bf(v);
        }
      } else if constexpr (EPI == 3) {
#pragma unroll
        for (int r = 0; r < 4; ++r) {
          const long gm = gmb + r;
          float v = acc[mt][nt][r] + bv;
          v = fmaxf(v, 0.0f);
          out[gm * N + gn] = f2bf(v);
        }
      } else {  // EPI == 4: fused QKV
        const int seg = gn >> 10;       // 0=Q, 1=K, 2=V  (uniform per block)
        const int nn = gn & 1023;
        if (seg == 0) {                 // Q plain (s,1024), pre-scaled
#pragma unroll
          for (int r = 0; r < 4; ++r)
            out[(gmb + r) * 1024 + nn] = f2bf((acc[mt][nt][r] + bv) * SCALE2);
        } else if (seg == 1) {          // K plain (s,1024)
#pragma unroll
          for (int r = 0; r < 4; ++r)
            (out + QOFF)[(gmb + r) * 1024 + nn] = f2bf(acc[mt][nt][r] + bv);
        } else {                        // V^T (b,h,d,s)
          const int h = nn >> 6, d = nn & 63;
          const long b = gmb >> 11;
          const int s = (int)(gmb & 2047);
          s16x4 pv;
#pragma unroll
          for (int r = 0; r < 4; ++r) pv[r] = (short)f2bf(acc[mt][nt][r] + bv);
          *(s16x4*)&(out + 2 * QOFF)[((b * 16 + h) * 64L + d) * 2048 + s] = pv;
        }
      }
    }
  }
}

// ---------------------------------------------------------------------------
// Flash attention, R7 (unchanged). One workgroup = 256 Q rows of one (b,h).
// KV tile = 64 rows, double-buffered, raw s_barrier + s_waitcnt vmcnt(4).
// ---------------------------------------------------------------------------
#define ATT_S 2048

__global__ __launch_bounds__(256)
__attribute__((amdgpu_waves_per_eu(2, 2))) void attn_fwd(
    const unsigned short* __restrict__ Q, const unsigned short* __restrict__ K,
    const unsigned short* __restrict__ VT, unsigned short* __restrict__ O) {
  __shared__ unsigned short SH[24576];  // 48 KB
  unsigned short* Kb0 = SH;             // [t][d] 64x64 swizzled
  unsigned short* Kb1 = SH + 4096;
  unsigned short* Vb0 = SH + 8192;      // [d][t] 64x64 swizzled
  unsigned short* Vb1 = SH + 12288;
  unsigned short* Pl  = SH + 16384;     // [m][t] 128x64 swizzled

  const int bh = blockIdx.y;
  const int q0 = blockIdx.x * 256;
  const long b = bh >> 4;
  const int h = bh & 15;
  const unsigned short* Qg = Q + (b * 2048) * 1024 + h * 64;
  const unsigned short* Kg = K + (b * 2048) * 1024 + h * 64;
  const unsigned short* Vg = VT + (long)bh * 64 * 2048;

  const int tid = threadIdx.x;
  const int wave = tid >> 6, lane = tid & 63;
  const int qd = lane >> 4, c = lane & 15;
  const int mb = wave * 32;

  const int srow = tid >> 3;
  const int sccs = ((tid & 7) ^ (srow & 7)) * 8;

  s16x8 qf[2][2][2];  // [half][mt][ks]
#pragma unroll
  for (int h2 = 0; h2 < 2; ++h2)
#pragma unroll
    for (int mt = 0; mt < 2; ++mt)
#pragma unroll
      for (int ks = 0; ks < 2; ++ks)
        qf[h2][mt][ks] = *(const s16x8*)&Qg[(long)(q0 + h2 * 128 + mb + mt * 16 + c) * 1024 +
                                            ks * 32 + qd * 8];

  s16x8 ones;
#pragma unroll
  for (int i = 0; i < 8; ++i) ones[i] = (short)0x3F80;

  f32x4 oacc[2][4][2] = {};  // [half][dt][mt]
  f32x4 lacc[2][2] = {};     // [half][mt]

  // preload tile 0
  gl2lds16(Kg + (long)srow * 1024 + sccs, &Kb0[tid * 8]);
  gl2lds16(Kg + (long)(srow + 32) * 1024 + sccs, &Kb0[(256 + tid) * 8]);
  gl2lds16(Vg + (long)srow * 2048 + sccs, &Vb0[tid * 8]);
  gl2lds16(Vg + (long)(srow + 32) * 2048 + sccs, &Vb0[(256 + tid) * 8]);

  for (int it = 0; it < 32; ++it) {
    const int p = it & 1;
    unsigned short* Kc = p ? Kb1 : Kb0;
    unsigned short* Vc = p ? Vb1 : Vb0;
    unsigned short* Kn = p ? Kb0 : Kb1;
    unsigned short* Vn = p ? Vb0 : Vb1;
    const int kvn = (it < 31) ? (it + 1) * 64 : 31 * 64;  // clamp keeps vmcnt math uniform
    gl2lds16(Kg + (long)(kvn + srow) * 1024 + sccs, &Kn[tid * 8]);
    gl2lds16(Kg + (long)(kvn + srow + 32) * 1024 + sccs, &Kn[(256 + tid) * 8]);
    gl2lds16(Vg + (long)srow * 2048 + kvn + sccs, &Vn[tid * 8]);
    gl2lds16(Vg + (long)(srow + 32) * 2048 + kvn + sccs, &Vn[(256 + tid) * 8]);

    // tile `it` fully landed; tile it+1's 4 loads stay in flight
    asm volatile("s_waitcnt vmcnt(4)\n\ts_barrier" ::: "memory");

#pragma unroll
    for (int h2 = 0; h2 < 2; ++h2) {
      f32x4 sacc[4][2] = {};
#pragma unroll
      for (int ks = 0; ks < 2; ++ks) {
        const int ch = ((ks * 4 + qd) ^ (c & 7)) * 8;
        s16x8 kf[4];
#pragma unroll
        for (int tt = 0; tt < 4; ++tt)
          kf[tt] = *(const s16x8*)&Kc[(tt * 16 + c) * 64 + ch];
#pragma unroll
        for (int mt = 0; mt < 2; ++mt)
#pragma unroll
          for (int tt = 0; tt < 4; ++tt)
            sacc[tt][mt] = mfma16(kf[tt], qf[h2][mt][ks], sacc[tt][mt]);
      }

      // exp2 + pack into wave-private P rows (8-chunk XOR swizzle, row len 64)
#pragma unroll
      for (int mt = 0; mt < 2; ++mt) {
        const int ml = mb + mt * 16 + c;
#pragma unroll
        for (int tt = 0; tt < 4; ++tt) {
          unsigned int pk[2];
          pk[0] = pkbf_trunc(__builtin_amdgcn_exp2f(sacc[tt][mt][0]),
                             __builtin_amdgcn_exp2f(sacc[tt][mt][1]));
          pk[1] = pkbf_trunc(__builtin_amdgcn_exp2f(sacc[tt][mt][2]),
                             __builtin_amdgcn_exp2f(sacc[tt][mt][3]));
          const int chw = ((tt * 2 + (qd >> 1)) ^ (ml & 7)) * 8 + (qd & 1) * 4;
          *(uint2*)&Pl[ml * 64 + chw] = *(uint2*)pk;
        }
      }
      asm volatile("s_waitcnt lgkmcnt(0)" ::: "memory");  // own-wave P visible

#pragma unroll
      for (int ks = 0; ks < 2; ++ks) {
        const int vch = ((ks * 4 + qd) ^ (c & 7)) * 8;
        s16x8 vf[4], pf[2];
#pragma unroll
        for (int dt = 0; dt < 4; ++dt)
          vf[dt] = *(const s16x8*)&Vc[(dt * 16 + c) * 64 + vch];
#pragma unroll
        for (int mt = 0; mt < 2; ++mt) {
          const int pr = mb + mt * 16 + c;
          pf[mt] = *(const s16x8*)&Pl[pr * 64 + (((ks * 4 + qd) ^ (pr & 7)) * 8)];
        }
#pragma unroll
        for (int mt = 0; mt < 2; ++mt) {
#pragma unroll
          for (int dt = 0; dt < 4; ++dt)
            oacc[h2][dt][mt] = mfma16(vf[dt], pf[mt], oacc[h2][dt][mt]);
          lacc[h2][mt] = mfma16(ones, pf[mt], lacc[h2][mt]);
        }
      }
    }

    // all waves done reading this buffer before next iter's prefetch hits it
    asm volatile("s_barrier" ::: "memory");
  }

#pragma unroll
  for (int h2 = 0; h2 < 2; ++h2)
#pragma unroll
    for (int mt = 0; mt < 2; ++mt) {
      const float inv = 1.0f / lacc[h2][mt][0];
      const int s = q0 + h2 * 128 + mb + mt * 16 + c;
      const long ob = (b * (long)ATT_S + s) * 1024L + h * 64;
#pragma unroll
      for (int dt = 0; dt < 4; ++dt) {
        s16x4 ov;
#pragma unroll
        for (int r = 0; r < 4; ++r) ov[r] = (short)f2bf(oacc[h2][dt][mt][r] * inv);
        *(s16x4*)&O[ob + dt * 16 + qd * 4] = ov;
      }
    }
}

// ---------------------------------------------------------------------------
template <bool FINAL>
__global__ __launch_bounds__(256) void norm_affine(
    const unsigned short* __restrict__ X, const unsigned short* __restrict__ av,
    const unsigned short* __restrict__ bv, void* __restrict__ outv,
    const int* __restrict__ flag) {
  const int row = blockIdx.x;
  const int s = row & 2047;
  const unsigned short* xr = X + (long)row * 1024;
  const int tid = threadIdx.x;
  const u16x4 u = *(const u16x4*)&xr[tid * 4];
  float v[4];
  float s1 = 0.f, s2 = 0.f;
#pragma unroll
  for (int i = 0; i < 4; ++i) {
    v[i] = bf2f(u[i]);
    s1 += v[i];
    s2 += v[i] * v[i];
  }
#pragma unroll
  for (int off = 32; off >= 1; off >>= 1) {
    s1 += __shfl_xor(s1, off);
    s2 += __shfl_xor(s2, off);
  }
  __shared__ float red[8];
  const int wave = tid >> 6, lane = tid & 63;
  if (lane == 0) {
    red[wave * 2] = s1;
    red[wave * 2 + 1] = s2;
  }
  __syncthreads();
  s1 = red[0] + red[2] + red[4] + red[6];
  s2 = red[1] + red[3] + red[5] + red[7];
  const float mean = s1 * (1.0f / 1024.0f);
  const float var = fmaxf(s2 * (1.0f / 1024.0f) - mean * mean, 0.0f);
  const float rstd = rsqrtf(var + 1e-5f);
  const float aa = bf2f(av[s]), bb = bf2f(bv[s]);
  float o[4];
#pragma unroll
  for (int i = 0; i < 4; ++i) o[i] = aa * (v[i] - mean) * rstd + bb;
  bool as_bf16 = true;
  if constexpr (FINAL) as_bf16 = (*flag != 0);
  if (as_bf16) {
    u16x4 ob;
#pragma unroll
    for (int i = 0; i < 4; ++i) ob[i] = f2bf(o[i]);
    *(u16x4*)&((unsigned short*)outv)[(long)row * 1024 + tid * 4] = ob;
  } else {
    float4 of = {o[0], o[1], o[2], o[3]};
    *(float4*)&((float*)outv)[(long)row * 1024 + tid * 4] = of;
  }
}

// ---------------------------------------------------------------------------
extern "C" void kernel_launch(void* const* d_in, const int* in_sizes, int n_in,
                              void* d_out, int out_size, void* d_ws, size_t ws_size,
                              hipStream_t stream) {
  char* ws = (char*)d_ws;
  const size_t SZ = 8192ull * 1024 * 2;
  const size_t WSZ = 1024ull * 1024 * 2;

  unsigned short* xb   = (unsigned short*)(ws);
  unsigned short* qb   = (unsigned short*)(ws + SZ);   // qb,kb,vtb contiguous
  unsigned short* kb   = (unsigned short*)(ws + 2 * SZ);
  unsigned short* vtb  = (unsigned short*)(ws + 3 * SZ);
  unsigned short* attn = (unsigned short*)(ws + 4 * SZ);
  unsigned short* hb   = (unsigned short*)(ws + 5 * SZ);
  unsigned short* r1   = qb;
  unsigned short* ffb  = kb;
  unsigned short* r2   = attn;

  char* wreg = ws + 6 * SZ;
  unsigned short* wqb = (unsigned short*)(wreg);
  unsigned short* w1b = (unsigned short*)(wreg + 4 * WSZ);
  unsigned short* w2b = (unsigned short*)(wreg + 6 * WSZ);
  unsigned short* wob = (unsigned short*)(wreg + 3 * WSZ);
  unsigned short* smal = (unsigned short*)(wreg + 8 * WSZ);
  unsigned short* bqb = smal;
  unsigned short* bkb = smal + 1024;
  unsigned short* bvb = smal + 2048;
  unsigned short* bob = smal + 3072;
  unsigned short* b1b = smal + 4096;
  unsigned short* b2b = smal + 6144;
  unsigned short* a1b = smal + 7168;
  unsigned short* g1b = smal + 9216;
  unsigned short* a2b = smal + 11264;
  unsigned short* g2b = smal + 13312;
  int* flag = (int*)(wreg + 8 * WSZ + 64 * 1024);

  CvtArgs ca;
  unsigned short* wkb = wqb + 1024 * 1024;
  unsigned short* wvb = wqb + 2 * 1024 * 1024;
  unsigned short* dsts[17] = {xb, wqb, bqb, wkb, bkb, wvb, bvb, wob, bob,
                              a1b, g1b, w1b, b1b, w2b, b2b, a2b, g2b};
  ca.cum4[0] = 0;
  for (int i = 0; i < 17; ++i) {
    ca.src[i] = d_in[i];
    ca.dst[i] = dsts[i];
    ca.cum4[i + 1] = ca.cum4[i] + in_sizes[i] / 4;
  }
  const int total4 = ca.cum4[17];

  // one-time: allow 128 KB dynamic LDS for the gemm2 instantiations
  static bool attr_set = false;
  if (!attr_set) {
    attr_set = true;
    hipFuncSetAttribute(reinterpret_cast<const void*>(gemm2<2>),
                        hipFuncAttributeMaxDynamicSharedMemorySize, 131072);
    hipFuncSetAttribute(reinterpret_cast<const void*>(gemm2<3>),
                        hipFuncAttributeMaxDynamicSharedMemorySize, 131072);
    hipFuncSetAttribute(reinterpret_cast<const void*>(gemm2<4>),
                        hipFuncAttributeMaxDynamicSharedMemorySize, 131072);
  }

  dim3 blk(256);
  dim3 blk512(512);
  const int GLDS = 131072;
  detect_dtype<<<1, blk, 0, stream>>>((const unsigned int*)d_in[0], flag);
  cvt_all<<<(total4 + 255) / 256, blk, 0, stream>>>(ca, flag, total4);

  gemm2<4><<<dim3(12, 32), blk512, GLDS, stream>>>(xb, wqb, bqb, nullptr, qb, 8192, 3072, 1024);
  attn_fwd<<<dim3(8, 64), blk, 0, stream>>>(qb, kb, vtb, attn);
  gemm2<2><<<dim3(4, 32), blk512, GLDS, stream>>>(attn, wob, bob, xb, r1, 8192, 1024, 1024);
  norm_affine<false><<<8192, blk, 0, stream>>>(r1, a1b, g1b, hb, nullptr);
  gemm2<3><<<dim3(8, 32), blk512, GLDS, stream>>>(hb, w1b, b1b, nullptr, ffb, 8192, 2048, 1024);
  gemm2<2><<<dim3(4, 32), blk512, GLDS, stream>>>(ffb, w2b, b2b, hb, r2, 8192, 1024, 2048);
  norm_affine<true><<<8192, blk, 0, stream>>>(r2, a2b, g2b, d_out, flag);
}

// Round 4
// 404.407 us; speedup vs baseline: 1.1346x; 1.1346x over previous
//
#include <hip/hip_runtime.h>

// ---------------------------------------------------------------------------
// TransformerBlock (B=4,S=2048,E=1024,H=16,Dh=64), fp32 (or bf16) in, fp32
// (or bf16) out — dtype auto-detected; all compute in bf16 MFMA w/ fp32 accum.
// Pipeline: cvt-to-bf16 -> fused QKV gemm -> flash attn -> Wo gemm (+x) ->
//           norm1 -> FFN1 (relu) -> FFN2 (+h) -> norm2 -> out
// R7: attn K/V double-buffer with raw s_barrier + s_waitcnt vmcnt(4).
// R11: GEMM fragment-read dedup (R3 read every A-frag and B-frag twice ->
//      0.75 ds_read_b128/MFMA -> LDS pipe 2.5x oversubscribed -> MfmaUtil 23%).
//      gemm2<EPI,BM>, BN=256 fixed:
//      BM=256 (QKV/FFN1): 2x64KB buffers; per K-step {read B(8)+A-q0(8);
//        stage B x4; 32 MFMA; vmcnt(4)+barrier; read A-q1(8); stage A x4;
//        32 MFMA} -> 24 reads / 64 MFMA, 2 barriers/step, waits counted.
//      BM=128 (Wo/FFN2, full-chip 256-wg grids): 3x48KB buffers, distance-2
//        prefetch, one vmcnt(6)+barrier per step, 16 reads / 32 MFMA.
// ---------------------------------------------------------------------------

typedef __attribute__((ext_vector_type(8))) short s16x8;
typedef __attribute__((ext_vector_type(4))) short s16x4;
typedef __attribute__((ext_vector_type(4))) unsigned short u16x4;
typedef __attribute__((ext_vector_type(4))) float f32x4;

__device__ __forceinline__ float bf2f(unsigned short u) {
  unsigned int v = ((unsigned int)u) << 16;
  return __builtin_bit_cast(float, v);
}
__device__ __forceinline__ unsigned short f2bf(float f) {
  unsigned int u = __builtin_bit_cast(unsigned int, f);
  u += 0x7fffu + ((u >> 16) & 1u);   // RNE
  return (unsigned short)(u >> 16);
}
// pack two f32 -> two bf16 (truncate) in one v_perm_b32
__device__ __forceinline__ unsigned int pkbf_trunc(float f0, float f1) {
  return __builtin_amdgcn_perm(__builtin_bit_cast(unsigned int, f1),
                               __builtin_bit_cast(unsigned int, f0), 0x07060302u);
}
__device__ __forceinline__ f32x4 mfma16(s16x8 a, s16x8 b, f32x4 c) {
  return __builtin_amdgcn_mfma_f32_16x16x32_bf16(a, b, c, 0, 0, 0);
}
__device__ __forceinline__ void gl2lds16(const unsigned short* g, unsigned short* l) {
  __builtin_amdgcn_global_load_lds(
      (const __attribute__((address_space(1))) unsigned int*)(g),
      (__attribute__((address_space(3))) unsigned int*)(l), 16, 0, 0);
}

// ---------------------------------------------------------------------------
__global__ void detect_dtype(const unsigned int* __restrict__ x, int* __restrict__ flag) {
  const int tid = threadIdx.x;
  int cnt = 0;
  for (int i = tid; i < 2048; i += 256) {
    const unsigned e = (x[i] >> 7) & 0xFF;
    cnt += (e >= 100 && e <= 150) ? 1 : 0;
  }
#pragma unroll
  for (int off = 32; off >= 1; off >>= 1) cnt += __shfl_xor(cnt, off);
  __shared__ int red[4];
  if ((tid & 63) == 0) red[tid >> 6] = cnt;
  __syncthreads();
  if (tid == 0) *flag = ((red[0] + red[1] + red[2] + red[3]) > 1536) ? 1 : 0;
}

// ---------------------------------------------------------------------------
struct CvtArgs {
  const void* src[17];
  unsigned short* dst[17];
  int cum4[18];
};

__global__ __launch_bounds__(256) void cvt_all(CvtArgs a, const int* __restrict__ flag, int total4) {
  const int i = blockIdx.x * 256 + threadIdx.x;
  if (i >= total4) return;
  int lo = 0, hi = 17;
  while (hi - lo > 1) {
    const int mid = (lo + hi) >> 1;
    if (i >= a.cum4[mid]) lo = mid; else hi = mid;
  }
  const int off4 = i - a.cum4[lo];
  if (*flag) {
    const u16x4* s = (const u16x4*)a.src[lo];
    *(u16x4*)&a.dst[lo][off4 * 4] = s[off4];
  } else {
    const float4* s = (const float4*)a.src[lo];
    const float4 v = s[off4];
    u16x4 o;
    o[0] = f2bf(v.x); o[1] = f2bf(v.y); o[2] = f2bf(v.z); o[3] = f2bf(v.w);
    *(u16x4*)&a.dst[lo][off4 * 4] = o;
  }
}

// ---------------------------------------------------------------------------
// GEMM: C = A(MxK) * W(NxK)^T + bias.  BN=256, BK=64, 512 threads,
// 8 waves 2Mx4N (per-wave (BM/2)x64).
// EPI 2: += resid. EPI 3: relu. EPI 4: fused QKV split (Q scaled, V^T scatter).
// ---------------------------------------------------------------------------
#define QOFF 8388608L
#define SCALE2 0.18033688011f  // (1/8) * log2(e)

template <int EPI, int BM>
__global__ __launch_bounds__(512, 1) void gemm2(
    const unsigned short* __restrict__ A, const unsigned short* __restrict__ W,
    const unsigned short* __restrict__ bias, const unsigned short* __restrict__ resid,
    unsigned short* __restrict__ out, int M, int N, int K) {
  constexpr int NBUF = (BM == 256) ? 2 : 3;
  constexpr int BUFE = (BM + 256) * 64;   // shorts per buffer
  extern __shared__ unsigned short sh[];

  const int tid = threadIdx.x;
  const int lane = tid & 63;
  const int wave = tid >> 6;
  const int qd = lane >> 4;
  const int c = lane & 15;
  const int wr = (wave >> 2) * (BM / 2);
  const int wc = (wave & 3) * 64;

  // XCD-bijective block swizzle (nwg % 8 == 0 for all our grids).
  const int nx = gridDim.x, ny = gridDim.y;
  const int nwg = nx * ny;
  int lin = blockIdx.y * nx + blockIdx.x;
  lin = (lin & 7) * (nwg >> 3) + (lin >> 3);
  const int by = lin % ny;            // M varies fastest within an XCD chunk
  const int bx = lin / ny;            // -> B-panel resident per XCD-L2
  const long m0 = (long)by * BM;
  const long n0 = (long)bx * 256;

  // staging: thread owns row (tid>>3) of a 64-row quarter, chunk tid&7,
  // source col XOR-swizzled so LDS dest stays linear; reads unswizzle.
  const int srow = tid >> 3;
  const int scc = ((tid & 7) ^ (srow & 7)) * 8;
  const unsigned short* Asrc = A + (m0 + srow) * (long)K + scc;
  const unsigned short* Wsrc = W + (n0 + srow) * (long)K + scc;
  const int lofs = tid * 8;

  f32x4 acc[BM / 32][4] = {};

  const int NT = K >> 6;

  auto stA = [&](int sel, int tt, int q) {
    gl2lds16(Asrc + (long)q * 64 * K + (long)tt * 64, sh + sel * BUFE + q * 4096 + lofs);
  };
  auto stB = [&](int sel, int tt, int q) {
    gl2lds16(Wsrc + (long)q * 64 * K + (long)tt * 64,
             sh + sel * BUFE + BM * 64 + q * 4096 + lofs);
  };

  // prologue (issue order = age order for the counted waits)
  if constexpr (BM == 256) {
    stB(0, 0, 0); stB(0, 0, 1); stB(0, 0, 2); stB(0, 0, 3);
    stA(0, 0, 0); stA(0, 0, 2); stA(0, 0, 1); stA(0, 0, 3);
  } else {
    stB(0, 0, 0); stB(0, 0, 1); stB(0, 0, 2); stB(0, 0, 3); stA(0, 0, 0); stA(0, 0, 1);
    stB(1, 1, 0); stB(1, 1, 1); stB(1, 1, 2); stB(1, 1, 3); stA(1, 1, 0); stA(1, 1, 1);
  }

  int cur = 0;
  for (int t = 0; t < NT; ++t) {
    const unsigned short* Ab = sh + cur * BUFE;
    const unsigned short* Bb = Ab + BM * 64;

    if constexpr (BM == 256) {
      const bool dost = (t + 1 < NT);
      const int ns = cur ^ 1;
      // B,A-q0,A-q2 of tile t landed; its A-q1,A-q3 (newest 2) still in flight
      asm volatile("s_waitcnt vmcnt(2)\n\ts_barrier" ::: "memory");
      s16x8 bfr[4][2], af[4][2];
#pragma unroll
      for (int nt = 0; nt < 4; ++nt)
#pragma unroll
        for (int ks = 0; ks < 2; ++ks)
          bfr[nt][ks] = *(const s16x8*)&Bb[(wc + nt * 16 + c) * 64 +
                                           (((ks * 4 + qd) ^ (c & 7)) * 8)];
#pragma unroll
      for (int mt = 0; mt < 4; ++mt)
#pragma unroll
        for (int ks = 0; ks < 2; ++ks)
          af[mt][ks] = *(const s16x8*)&Ab[(wr + mt * 16 + c) * 64 +
                                          (((ks * 4 + qd) ^ (c & 7)) * 8)];
      if (dost) { stB(ns, t + 1, 0); stB(ns, t + 1, 1); stB(ns, t + 1, 2); stB(ns, t + 1, 3); }
      __builtin_amdgcn_s_setprio(1);
#pragma unroll
      for (int mt = 0; mt < 4; ++mt)
#pragma unroll
        for (int nt = 0; nt < 4; ++nt)
#pragma unroll
          for (int ks = 0; ks < 2; ++ks)
            acc[mt][nt] = mfma16(af[mt][ks], bfr[nt][ks], acc[mt][nt]);
      __builtin_amdgcn_s_setprio(0);
      // drain tile t's A-q1/A-q3 (leave t+1's 4 B loads in flight)
      if (dost) asm volatile("s_waitcnt vmcnt(4)\n\ts_barrier" ::: "memory");
      else      asm volatile("s_waitcnt vmcnt(0)\n\ts_barrier" ::: "memory");
#pragma unroll
      for (int mt = 0; mt < 4; ++mt)
#pragma unroll
        for (int ks = 0; ks < 2; ++ks)
          af[mt][ks] = *(const s16x8*)&Ab[(wr + 64 + mt * 16 + c) * 64 +
                                          (((ks * 4 + qd) ^ (c & 7)) * 8)];
      if (dost) { stA(ns, t + 1, 0); stA(ns, t + 1, 2); stA(ns, t + 1, 1); stA(ns, t + 1, 3); }
      __builtin_amdgcn_s_setprio(1);
#pragma unroll
      for (int mt = 0; mt < 4; ++mt)
#pragma unroll
        for (int nt = 0; nt < 4; ++nt)
#pragma unroll
          for (int ks = 0; ks < 2; ++ks)
            acc[4 + mt][nt] = mfma16(af[mt][ks], bfr[nt][ks], acc[4 + mt][nt]);
      __builtin_amdgcn_s_setprio(0);
    } else {
      // tile t landed; tile t+1's 6 loads stay in flight
      if (t + 1 < NT) asm volatile("s_waitcnt vmcnt(6)\n\ts_barrier" ::: "memory");
      else            asm volatile("s_waitcnt vmcnt(0)\n\ts_barrier" ::: "memory");
      s16x8 bfr[4][2], af[4][2];
#pragma unroll
      for (int nt = 0; nt < 4; ++nt)
#pragma unroll
        for (int ks = 0; ks < 2; ++ks)
          bfr[nt][ks] = *(const s16x8*)&Bb[(wc + nt * 16 + c) * 64 +
                                           (((ks * 4 + qd) ^ (c & 7)) * 8)];
#pragma unroll
      for (int mt = 0; mt < 4; ++mt)
#pragma unroll
        for (int ks = 0; ks < 2; ++ks)
          af[mt][ks] = *(const s16x8*)&Ab[(wr + mt * 16 + c) * 64 +
                                          (((ks * 4 + qd) ^ (c & 7)) * 8)];
      if (t + 2 < NT) {
        const int ns = (cur >= 1) ? cur - 1 : 2;   // (cur+2)%3
        stB(ns, t + 2, 0); stB(ns, t + 2, 1); stB(ns, t + 2, 2); stB(ns, t + 2, 3);
        stA(ns, t + 2, 0); stA(ns, t + 2, 1);
      }
      __builtin_amdgcn_s_setprio(1);
#pragma unroll
      for (int mt = 0; mt < 4; ++mt)
#pragma unroll
        for (int nt = 0; nt < 4; ++nt)
#pragma unroll
          for (int ks = 0; ks < 2; ++ks)
            acc[mt][nt] = mfma16(af[mt][ks], bfr[nt][ks], acc[mt][nt]);
      __builtin_amdgcn_s_setprio(0);
    }
    cur = (cur + 1 == NBUF) ? 0 : cur + 1;
  }

#pragma unroll
  for (int nt = 0; nt < 4; ++nt) {
    const int gn = (int)n0 + wc + nt * 16 + c;
    const float bv = bf2f(bias[gn]);
#pragma unroll
    for (int mt = 0; mt < BM / 32; ++mt) {
      const long gmb = m0 + wr + mt * 16 + qd * 4;
      if constexpr (EPI == 2) {
#pragma unroll
        for (int r = 0; r < 4; ++r) {
          const long gm = gmb + r;
          const float v = acc[mt][nt][r] + bv + bf2f(resid[gm * N + gn]);
          out[gm * N + gn] = f2bf(v);
        }
      } else if constexpr (EPI == 3) {
#pragma unroll
        for (int r = 0; r < 4; ++r) {
          const long gm = gmb + r;
          float v = acc[mt][nt][r] + bv;
          v = fmaxf(v, 0.0f);
          out[gm * N + gn] = f2bf(v);
        }
      } else {  // EPI == 4: fused QKV
        const int seg = gn >> 10;       // 0=Q, 1=K, 2=V  (uniform per block)
        const int nn = gn & 1023;
        if (seg == 0) {                 // Q plain (s,1024), pre-scaled
#pragma unroll
          for (int r = 0; r < 4; ++r)
            out[(gmb + r) * 1024 + nn] = f2bf((acc[mt][nt][r] + bv) * SCALE2);
        } else if (seg == 1) {          // K plain (s,1024)
#pragma unroll
          for (int r = 0; r < 4; ++r)
            (out + QOFF)[(gmb + r) * 1024 + nn] = f2bf(acc[mt][nt][r] + bv);
        } else {                        // V^T (b,h,d,s)
          const int h = nn >> 6, d = nn & 63;
          const long b = gmb >> 11;
          const int s = (int)(gmb & 2047);
          s16x4 pv;
#pragma unroll
          for (int r = 0; r < 4; ++r) pv[r] = (short)f2bf(acc[mt][nt][r] + bv);
          *(s16x4*)&(out + 2 * QOFF)[((b * 16 + h) * 64L + d) * 2048 + s] = pv;
        }
      }
    }
  }
}

// ---------------------------------------------------------------------------
// Flash attention, R7 (unchanged). One workgroup = 256 Q rows of one (b,h).
// KV tile = 64 rows, double-buffered, raw s_barrier + s_waitcnt vmcnt(4).
// ---------------------------------------------------------------------------
#define ATT_S 2048

__global__ __launch_bounds__(256)
__attribute__((amdgpu_waves_per_eu(2, 2))) void attn_fwd(
    const unsigned short* __restrict__ Q, const unsigned short* __restrict__ K,
    const unsigned short* __restrict__ VT, unsigned short* __restrict__ O) {
  __shared__ unsigned short SH[24576];  // 48 KB
  unsigned short* Kb0 = SH;             // [t][d] 64x64 swizzled
  unsigned short* Kb1 = SH + 4096;
  unsigned short* Vb0 = SH + 8192;      // [d][t] 64x64 swizzled
  unsigned short* Vb1 = SH + 12288;
  unsigned short* Pl  = SH + 16384;     // [m][t] 128x64 swizzled

  const int bh = blockIdx.y;
  const int q0 = blockIdx.x * 256;
  const long b = bh >> 4;
  const int h = bh & 15;
  const unsigned short* Qg = Q + (b * 2048) * 1024 + h * 64;
  const unsigned short* Kg = K + (b * 2048) * 1024 + h * 64;
  const unsigned short* Vg = VT + (long)bh * 64 * 2048;

  const int tid = threadIdx.x;
  const int wave = tid >> 6, lane = tid & 63;
  const int qd = lane >> 4, c = lane & 15;
  const int mb = wave * 32;

  const int srow = tid >> 3;
  const int sccs = ((tid & 7) ^ (srow & 7)) * 8;

  s16x8 qf[2][2][2];  // [half][mt][ks]
#pragma unroll
  for (int h2 = 0; h2 < 2; ++h2)
#pragma unroll
    for (int mt = 0; mt < 2; ++mt)
#pragma unroll
      for (int ks = 0; ks < 2; ++ks)
        qf[h2][mt][ks] = *(const s16x8*)&Qg[(long)(q0 + h2 * 128 + mb + mt * 16 + c) * 1024 +
                                            ks * 32 + qd * 8];

  s16x8 ones;
#pragma unroll
  for (int i = 0; i < 8; ++i) ones[i] = (short)0x3F80;

  f32x4 oacc[2][4][2] = {};  // [half][dt][mt]
  f32x4 lacc[2][2] = {};     // [half][mt]

  // preload tile 0
  gl2lds16(Kg + (long)srow * 1024 + sccs, &Kb0[tid * 8]);
  gl2lds16(Kg + (long)(srow + 32) * 1024 + sccs, &Kb0[(256 + tid) * 8]);
  gl2lds16(Vg + (long)srow * 2048 + sccs, &Vb0[tid * 8]);
  gl2lds16(Vg + (long)(srow + 32) * 2048 + sccs, &Vb0[(256 + tid) * 8]);

  for (int it = 0; it < 32; ++it) {
    const int p = it & 1;
    unsigned short* Kc = p ? Kb1 : Kb0;
    unsigned short* Vc = p ? Vb1 : Vb0;
    unsigned short* Kn = p ? Kb0 : Kb1;
    unsigned short* Vn = p ? Vb0 : Vb1;
    const int kvn = (it < 31) ? (it + 1) * 64 : 31 * 64;  // clamp keeps vmcnt math uniform
    gl2lds16(Kg + (long)(kvn + srow) * 1024 + sccs, &Kn[tid * 8]);
    gl2lds16(Kg + (long)(kvn + srow + 32) * 1024 + sccs, &Kn[(256 + tid) * 8]);
    gl2lds16(Vg + (long)srow * 2048 + kvn + sccs, &Vn[tid * 8]);
    gl2lds16(Vg + (long)(srow + 32) * 2048 + kvn + sccs, &Vn[(256 + tid) * 8]);

    // tile `it` fully landed; tile it+1's 4 loads stay in flight
    asm volatile("s_waitcnt vmcnt(4)\n\ts_barrier" ::: "memory");

#pragma unroll
    for (int h2 = 0; h2 < 2; ++h2) {
      f32x4 sacc[4][2] = {};
#pragma unroll
      for (int ks = 0; ks < 2; ++ks) {
        const int ch = ((ks * 4 + qd) ^ (c & 7)) * 8;
        s16x8 kf[4];
#pragma unroll
        for (int tt = 0; tt < 4; ++tt)
          kf[tt] = *(const s16x8*)&Kc[(tt * 16 + c) * 64 + ch];
#pragma unroll
        for (int mt = 0; mt < 2; ++mt)
#pragma unroll
          for (int tt = 0; tt < 4; ++tt)
            sacc[tt][mt] = mfma16(kf[tt], qf[h2][mt][ks], sacc[tt][mt]);
      }

      // exp2 + pack into wave-private P rows (8-chunk XOR swizzle, row len 64)
#pragma unroll
      for (int mt = 0; mt < 2; ++mt) {
        const int ml = mb + mt * 16 + c;
#pragma unroll
        for (int tt = 0; tt < 4; ++tt) {
          unsigned int pk[2];
          pk[0] = pkbf_trunc(__builtin_amdgcn_exp2f(sacc[tt][mt][0]),
                             __builtin_amdgcn_exp2f(sacc[tt][mt][1]));
          pk[1] = pkbf_trunc(__builtin_amdgcn_exp2f(sacc[tt][mt][2]),
                             __builtin_amdgcn_exp2f(sacc[tt][mt][3]));
          const int chw = ((tt * 2 + (qd >> 1)) ^ (ml & 7)) * 8 + (qd & 1) * 4;
          *(uint2*)&Pl[ml * 64 + chw] = *(uint2*)pk;
        }
      }
      asm volatile("s_waitcnt lgkmcnt(0)" ::: "memory");  // own-wave P visible

#pragma unroll
      for (int ks = 0; ks < 2; ++ks) {
        const int vch = ((ks * 4 + qd) ^ (c & 7)) * 8;
        s16x8 vf[4], pf[2];
#pragma unroll
        for (int dt = 0; dt < 4; ++dt)
          vf[dt] = *(const s16x8*)&Vc[(dt * 16 + c) * 64 + vch];
#pragma unroll
        for (int mt = 0; mt < 2; ++mt) {
          const int pr = mb + mt * 16 + c;
          pf[mt] = *(const s16x8*)&Pl[pr * 64 + (((ks * 4 + qd) ^ (pr & 7)) * 8)];
        }
#pragma unroll
        for (int mt = 0; mt < 2; ++mt) {
#pragma unroll
          for (int dt = 0; dt < 4; ++dt)
            oacc[h2][dt][mt] = mfma16(vf[dt], pf[mt], oacc[h2][dt][mt]);
          lacc[h2][mt] = mfma16(ones, pf[mt], lacc[h2][mt]);
        }
      }
    }

    // all waves done reading this buffer before next iter's prefetch hits it
    asm volatile("s_barrier" ::: "memory");
  }

#pragma unroll
  for (int h2 = 0; h2 < 2; ++h2)
#pragma unroll
    for (int mt = 0; mt < 2; ++mt) {
      const float inv = 1.0f / lacc[h2][mt][0];
      const int s = q0 + h2 * 128 + mb + mt * 16 + c;
      const long ob = (b * (long)ATT_S + s) * 1024L + h * 64;
#pragma unroll
      for (int dt = 0; dt < 4; ++dt) {
        s16x4 ov;
#pragma unroll
        for (int r = 0; r < 4; ++r) ov[r] = (short)f2bf(oacc[h2][dt][mt][r] * inv);
        *(s16x4*)&O[ob + dt * 16 + qd * 4] = ov;
      }
    }
}

// ---------------------------------------------------------------------------
template <bool FINAL>
__global__ __launch_bounds__(256) void norm_affine(
    const unsigned short* __restrict__ X, const unsigned short* __restrict__ av,
    const unsigned short* __restrict__ bv, void* __restrict__ outv,
    const int* __restrict__ flag) {
  const int row = blockIdx.x;
  const int s = row & 2047;
  const unsigned short* xr = X + (long)row * 1024;
  const int tid = threadIdx.x;
  const u16x4 u = *(const u16x4*)&xr[tid * 4];
  float v[4];
  float s1 = 0.f, s2 = 0.f;
#pragma unroll
  for (int i = 0; i < 4; ++i) {
    v[i] = bf2f(u[i]);
    s1 += v[i];
    s2 += v[i] * v[i];
  }
#pragma unroll
  for (int off = 32; off >= 1; off >>= 1) {
    s1 += __shfl_xor(s1, off);
    s2 += __shfl_xor(s2, off);
  }
  __shared__ float red[8];
  const int wave = tid >> 6, lane = tid & 63;
  if (lane == 0) {
    red[wave * 2] = s1;
    red[wave * 2 + 1] = s2;
  }
  __syncthreads();
  s1 = red[0] + red[2] + red[4] + red[6];
  s2 = red[1] + red[3] + red[5] + red[7];
  const float mean = s1 * (1.0f / 1024.0f);
  const float var = fmaxf(s2 * (1.0f / 1024.0f) - mean * mean, 0.0f);
  const float rstd = rsqrtf(var + 1e-5f);
  const float aa = bf2f(av[s]), bb = bf2f(bv[s]);
  float o[4];
#pragma unroll
  for (int i = 0; i < 4; ++i) o[i] = aa * (v[i] - mean) * rstd + bb;
  bool as_bf16 = true;
  if constexpr (FINAL) as_bf16 = (*flag != 0);
  if (as_bf16) {
    u16x4 ob;
#pragma unroll
    for (int i = 0; i < 4; ++i) ob[i] = f2bf(o[i]);
    *(u16x4*)&((unsigned short*)outv)[(long)row * 1024 + tid * 4] = ob;
  } else {
    float4 of = {o[0], o[1], o[2], o[3]};
    *(float4*)&((float*)outv)[(long)row * 1024 + tid * 4] = of;
  }
}

// ---------------------------------------------------------------------------
extern "C" void kernel_launch(void* const* d_in, const int* in_sizes, int n_in,
                              void* d_out, int out_size, void* d_ws, size_t ws_size,
                              hipStream_t stream) {
  char* ws = (char*)d_ws;
  const size_t SZ = 8192ull * 1024 * 2;
  const size_t WSZ = 1024ull * 1024 * 2;

  unsigned short* xb   = (unsigned short*)(ws);
  unsigned short* qb   = (unsigned short*)(ws + SZ);   // qb,kb,vtb contiguous
  unsigned short* kb   = (unsigned short*)(ws + 2 * SZ);
  unsigned short* vtb  = (unsigned short*)(ws + 3 * SZ);
  unsigned short* attn = (unsigned short*)(ws + 4 * SZ);
  unsigned short* hb   = (unsigned short*)(ws + 5 * SZ);
  unsigned short* r1   = qb;
  unsigned short* ffb  = kb;
  unsigned short* r2   = attn;

  char* wreg = ws + 6 * SZ;
  unsigned short* wqb = (unsigned short*)(wreg);
  unsigned short* w1b = (unsigned short*)(wreg + 4 * WSZ);
  unsigned short* w2b = (unsigned short*)(wreg + 6 * WSZ);
  unsigned short* wob = (unsigned short*)(wreg + 3 * WSZ);
  unsigned short* smal = (unsigned short*)(wreg + 8 * WSZ);
  unsigned short* bqb = smal;
  unsigned short* bkb = smal + 1024;
  unsigned short* bvb = smal + 2048;
  unsigned short* bob = smal + 3072;
  unsigned short* b1b = smal + 4096;
  unsigned short* b2b = smal + 6144;
  unsigned short* a1b = smal + 7168;
  unsigned short* g1b = smal + 9216;
  unsigned short* a2b = smal + 11264;
  unsigned short* g2b = smal + 13312;
  int* flag = (int*)(wreg + 8 * WSZ + 64 * 1024);

  CvtArgs ca;
  unsigned short* wkb = wqb + 1024 * 1024;
  unsigned short* wvb = wqb + 2 * 1024 * 1024;
  unsigned short* dsts[17] = {xb, wqb, bqb, wkb, bkb, wvb, bvb, wob, bob,
                              a1b, g1b, w1b, b1b, w2b, b2b, a2b, g2b};
  ca.cum4[0] = 0;
  for (int i = 0; i < 17; ++i) {
    ca.src[i] = d_in[i];
    ca.dst[i] = dsts[i];
    ca.cum4[i + 1] = ca.cum4[i] + in_sizes[i] / 4;
  }
  const int total4 = ca.cum4[17];

  // one-time: allow big dynamic LDS for the gemm2 instantiations
  static bool attr_set = false;
  if (!attr_set) {
    attr_set = true;
    hipFuncSetAttribute(reinterpret_cast<const void*>(gemm2<4, 256>),
                        hipFuncAttributeMaxDynamicSharedMemorySize, 131072);
    hipFuncSetAttribute(reinterpret_cast<const void*>(gemm2<3, 256>),
                        hipFuncAttributeMaxDynamicSharedMemorySize, 131072);
    hipFuncSetAttribute(reinterpret_cast<const void*>(gemm2<2, 128>),
                        hipFuncAttributeMaxDynamicSharedMemorySize, 147456);
  }

  dim3 blk(256);
  dim3 blk512(512);
  detect_dtype<<<1, blk, 0, stream>>>((const unsigned int*)d_in[0], flag);
  cvt_all<<<(total4 + 255) / 256, blk, 0, stream>>>(ca, flag, total4);

  gemm2<4, 256><<<dim3(12, 32), blk512, 131072, stream>>>(xb, wqb, bqb, nullptr, qb, 8192, 3072, 1024);
  attn_fwd<<<dim3(8, 64), blk, 0, stream>>>(qb, kb, vtb, attn);
  gemm2<2, 128><<<dim3(4, 64), blk512, 147456, stream>>>(attn, wob, bob, xb, r1, 8192, 1024, 1024);
  norm_affine<false><<<8192, blk, 0, stream>>>(r1, a1b, g1b, hb, nullptr);
  gemm2<3, 256><<<dim3(8, 32), blk512, 131072, stream>>>(hb, w1b, b1b, nullptr, ffb, 8192, 2048, 1024);
  gemm2<2, 128><<<dim3(4, 64), blk512, 147456, stream>>>(ffb, w2b, b2b, hb, r2, 8192, 1024, 2048);
  norm_affine<true><<<8192, blk, 0, stream>>>(r2, a2b, g2b, d_out, flag);
}